// Round 4
// baseline (326.038 us; speedup 1.0000x reference)
//
#include <hip/hip_runtime.h>
#include <hip/hip_bf16.h>

typedef __attribute__((ext_vector_type(8))) short bf16x8;
typedef __attribute__((ext_vector_type(4))) float f32x4;

static __device__ __forceinline__ f32x4 mfma16(bf16x8 a, bf16x8 b, f32x4 c) {
    return __builtin_amdgcn_mfma_f32_16x16x32_bf16(a, b, c, 0, 0, 0);
}

#define LOG2E 1.44269504f

static __device__ __forceinline__ __hip_bfloat16 f2bf(float f) { return __float2bfloat16(f); }

// ---------------- Kernel 0: prep ----------------
// y<4: transpose x[b][c][n] f32 -> xT[b][n][c] bf16 ; y==4: wb = bf16(qkv_w)
__global__ __launch_bounds__(256, 4) void prep_kernel(
    const float* __restrict__ x, const float* __restrict__ qkv_w,
    __hip_bfloat16* __restrict__ xT, __hip_bfloat16* __restrict__ wb)
{
    const int tid = threadIdx.x;
    if (blockIdx.y == 4) {
        int idx = (blockIdx.z * 64 + blockIdx.x) * 256 + tid;
        if (idx < 24576) {
            const float* s = qkv_w + (size_t)idx * 8;
            float4 f0 = *(const float4*)s, f1 = *(const float4*)(s + 4);
            union { bf16x8 v; __hip_bfloat16 h[8]; } u;
            u.h[0]=f2bf(f0.x); u.h[1]=f2bf(f0.y); u.h[2]=f2bf(f0.z); u.h[3]=f2bf(f0.w);
            u.h[4]=f2bf(f1.x); u.h[5]=f2bf(f1.y); u.h[6]=f2bf(f1.z); u.h[7]=f2bf(f1.w);
            *(bf16x8*)(wb + (size_t)idx * 8) = u.v;
        }
        return;
    }
    alignas(16) __shared__ __hip_bfloat16 sT[64 * 72];
    const int n0 = blockIdx.x * 64, c0 = blockIdx.y * 64, b = blockIdx.z;
    {
        int cc = tid >> 2, nq = (tid & 3) * 16;
        const float* src = x + ((size_t)b * 256 + c0 + cc) * 4096 + n0 + nq;
        #pragma unroll
        for (int i = 0; i < 4; i++) {
            float4 f = *(const float4*)(src + i * 4);
            sT[(nq + 4*i + 0) * 72 + cc] = f2bf(f.x);
            sT[(nq + 4*i + 1) * 72 + cc] = f2bf(f.y);
            sT[(nq + 4*i + 2) * 72 + cc] = f2bf(f.z);
            sT[(nq + 4*i + 3) * 72 + cc] = f2bf(f.w);
        }
    }
    __syncthreads();
    {
        int nl = tid >> 2, ch = (tid & 3) * 16;
        bf16x8 v0 = *(const bf16x8*)&sT[nl * 72 + ch];
        bf16x8 v1 = *(const bf16x8*)&sT[nl * 72 + ch + 8];
        __hip_bfloat16* dst = xT + ((size_t)b * 4096 + n0 + nl) * 256 + c0 + ch;
        *(bf16x8*)dst = v0;
        *(bf16x8*)(dst + 8) = v1;
    }
}

// ---------------- Kernel 1: QKV projection (no LDS, no barriers) ----------------
// q/k blocks compute D[n][o] (epilogue rows n, d contiguous); v blocks D[o][n].
__global__ __launch_bounds__(256, 4) void qkv_kernel(
    const __hip_bfloat16* __restrict__ xT, const __hip_bfloat16* __restrict__ wb,
    __hip_bfloat16* __restrict__ qb, __hip_bfloat16* __restrict__ kb,
    __hip_bfloat16* __restrict__ vt)
{
    const int nb = blockIdx.x * 64, obq = blockIdx.y, b = blockIdx.z;
    const int tid = threadIdx.x, lane = tid & 63, g = tid >> 6;
    const int quad = lane >> 4, l16 = lane & 15;
    const bool isV = (obq >= 8);

    const __hip_bfloat16* xb = xT + ((size_t)b * 4096 + nb) * 256;
    const __hip_bfloat16* wB = wb + (size_t)obq * 64 * 256;
    const __hip_bfloat16* aB = isV ? wB : xb;
    const __hip_bfloat16* bB = isV ? xb : wB;
    const __hip_bfloat16* aRow = aB + (size_t)(16 * g + l16) * 256;

    f32x4 acc[4];
    #pragma unroll
    for (int i = 0; i < 4; i++) acc[i] = (f32x4)0.f;

    #pragma unroll
    for (int c0 = 0; c0 < 256; c0 += 32) {
        bf16x8 af0 = *(const bf16x8*)&aRow[c0 + quad * 8];
        #pragma unroll
        for (int ct = 0; ct < 4; ct++) {
            bf16x8 bfv = *(const bf16x8*)&bB[(size_t)(16 * ct + l16) * 256 + c0 + quad * 8];
            acc[ct] = mfma16(af0, bfv, acc[ct]);
        }
    }

    if (!isV) {
        int proj = obq >> 2;
        int bh = b * 4 + (obq & 3);
        __hip_bfloat16* dst = (proj ? kb : qb) + (size_t)bh * 4096 * 64;
        #pragma unroll
        for (int ct = 0; ct < 4; ct++) {
            int d = 16 * ct + l16;
            #pragma unroll
            for (int r = 0; r < 4; r++) {
                int n = nb + 16 * g + 4 * quad + r;
                dst[(size_t)n * 64 + d] = f2bf(acc[ct][r]);
            }
        }
    } else {
        int bh = b * 4 + (obq - 8);
        #pragma unroll
        for (int ct = 0; ct < 4; ct++) {
            int n = nb + 16 * ct + l16;
            #pragma unroll
            for (int r = 0; r < 4; r++) {
                int d = 16 * g + 4 * quad + r;
                vt[((size_t)(bh * 64 + d)) * 4096 + n] = f2bf(acc[ct][r]);
            }
        }
    }
}

// ---------------- Kernel 2: transposed flash attention, barrier-free K-loop ----------------
// S^T = K.Q^T : C-layout col = query w, row = key. lsum per-lane scalar; P^T writes
// b64-packed; K/V/Q fragments direct from global (no staging, no main-loop barriers).
__global__ __launch_bounds__(512, 4) void attn_kernel(
    const __hip_bfloat16* __restrict__ qb, const __hip_bfloat16* __restrict__ kb,
    const __hip_bfloat16* __restrict__ vt, const float* __restrict__ hrel,
    const float* __restrict__ wrel, float* __restrict__ out)
{
    alignas(16) __shared__ unsigned char sBraw[36352];        // union region
    alignas(16) __shared__ __hip_bfloat16 sRH[64 * 68];       // persistent rh bias
    __hip_bfloat16* sW   = (__hip_bfloat16*)sBraw;            // 128x72 wrel
    __hip_bfloat16* sHRs = (__hip_bfloat16*)(sBraw + 18432);  // 64x72 shifted hrel
    __hip_bfloat16* sRWt = (__hip_bfloat16*)(sBraw + 27648);  // 64x68 rw scratch
    __hip_bfloat16* sPT  = (__hip_bfloat16*)sBraw;            // 8 waves x 16x72
    float* sOx = (float*)sBraw;                               // 64x65 combine
    float* slx = (float*)(sBraw + 16640);                     // 64

    const int h = blockIdx.x, bh = blockIdx.y;
    const int tid = threadIdx.x, lane = tid & 63;
    const int wv = tid >> 6, half = wv >> 2, g = wv & 3;
    const int quad = lane >> 4, l16 = lane & 15;
    const int w = 16 * g + l16;              // this lane's query column

    // ---- stage wrel (row 127 zero) and shifted hrel ----
    {
        int r = tid >> 2, c0 = (tid & 3) << 4;
        union { bf16x8 v; __hip_bfloat16 h8[8]; } u0, u1;
        #pragma unroll
        for (int i = 0; i < 2; i++) {
            float4 f = (r < 127) ? *(const float4*)&wrel[r * 64 + c0 + 4*i] : float4{0,0,0,0};
            u0.h8[4*i+0]=f2bf(f.x); u0.h8[4*i+1]=f2bf(f.y); u0.h8[4*i+2]=f2bf(f.z); u0.h8[4*i+3]=f2bf(f.w);
        }
        #pragma unroll
        for (int i = 0; i < 2; i++) {
            float4 f = (r < 127) ? *(const float4*)&wrel[r * 64 + c0 + 8 + 4*i] : float4{0,0,0,0};
            u1.h8[4*i+0]=f2bf(f.x); u1.h8[4*i+1]=f2bf(f.y); u1.h8[4*i+2]=f2bf(f.z); u1.h8[4*i+3]=f2bf(f.w);
        }
        *(bf16x8*)&sW[r * 72 + c0]     = u0.v;
        *(bf16x8*)&sW[r * 72 + c0 + 8] = u1.v;
    }
    {
        int r = tid >> 3, c0 = (tid & 7) << 3;
        union { bf16x8 v; __hip_bfloat16 h8[8]; } u0;
        #pragma unroll
        for (int i = 0; i < 2; i++) {
            float4 f = *(const float4*)&hrel[(63 - h + r) * 64 + c0 + 4*i];
            u0.h8[4*i+0]=f2bf(f.x); u0.h8[4*i+1]=f2bf(f.y); u0.h8[4*i+2]=f2bf(f.z); u0.h8[4*i+3]=f2bf(f.w);
        }
        *(bf16x8*)&sHRs[r * 72 + c0] = u0.v;
    }

    // Q fragments for this lane's row w (B-operand of every MFMA), direct global
    const __hip_bfloat16* qsrc = qb + ((size_t)bh * 4096 + h * 64) * 64;
    bf16x8 qf0 = *(const bf16x8*)&qsrc[w * 64 + quad * 8];
    bf16x8 qf1 = *(const bf16x8*)&qsrc[w * 64 + 32 + quad * 8];
    __syncthreads();   // staging -> prologue MFMAs

    // rw: X^T[rr][w] = wrel[rr].q[w]; scatter wp = rr + w - 63 into sRWt[w][wp]
    {
        const int rbase = half * 64;
        #pragma unroll
        for (int ct = 0; ct < 4; ct++) {
            f32x4 a = (f32x4)0.f;
            a = mfma16(*(const bf16x8*)&sW[(rbase + 16*ct + l16) * 72 + quad * 8], qf0, a);
            a = mfma16(*(const bf16x8*)&sW[(rbase + 16*ct + l16) * 72 + 32 + quad * 8], qf1, a);
            #pragma unroll
            for (int r = 0; r < 4; r++) {
                int rr = rbase + 16 * ct + 4 * quad + r;
                int wp = rr + w - 63;
                if (wp >= 0 && wp < 64) sRWt[w * 68 + wp] = f2bf(a[r]);
            }
        }
    }
    // rh (half 0 only): rhT[h'][w] -> sRH[w][h'], b64-packed
    if (half == 0) {
        #pragma unroll
        for (int ct = 0; ct < 4; ct++) {
            f32x4 a = (f32x4)0.f;
            a = mfma16(*(const bf16x8*)&sHRs[(16*ct + l16) * 72 + quad * 8], qf0, a);
            a = mfma16(*(const bf16x8*)&sHRs[(16*ct + l16) * 72 + 32 + quad * 8], qf1, a);
            union { uint2 u; __hip_bfloat16 h4[4]; } pu;
            pu.h4[0]=f2bf(a[0]); pu.h4[1]=f2bf(a[1]); pu.h4[2]=f2bf(a[2]); pu.h4[3]=f2bf(a[3]);
            *(uint2*)&sRH[w * 68 + 16 * ct + 4 * quad] = pu.u;
        }
    }
    __syncthreads();   // prologue MFMAs done; sW region free for sPT

    // rw bias to registers (pre-scaled by log2 e)
    float rwreg[4][4];
    #pragma unroll
    for (int ct = 0; ct < 4; ct++) {
        union { uint2 u; __hip_bfloat16 h4[4]; } pu;
        pu.u = *(const uint2*)&sRWt[w * 68 + 16 * ct + 4 * quad];
        #pragma unroll
        for (int r = 0; r < 4; r++) rwreg[ct][r] = LOG2E * __bfloat162float(pu.h4[r]);
    }

    f32x4 oacc[4];
    #pragma unroll
    for (int i = 0; i < 4; i++) oacc[i] = (f32x4)0.f;
    float ls[4] = {0.f, 0.f, 0.f, 0.f};

    const __hip_bfloat16* ksrc = kb + (size_t)bh * 4096 * 64;
    const __hip_bfloat16* vsrc = vt + (size_t)bh * 64 * 4096;
    __hip_bfloat16* myPT = sPT + wv * 16 * 72;
    const float SC2 = 0.125f * LOG2E;

    for (int j = 0; j < 32; j++) {
        const int jr = half * 32 + j;
        const __hip_bfloat16* kj = ksrc + (size_t)jr * 64 * 64;

        // S^T = K . Q^T   (A = K frags direct from global)
        f32x4 sacc[4];
        #pragma unroll
        for (int ct = 0; ct < 4; ct++) {
            bf16x8 k0 = *(const bf16x8*)&kj[(size_t)(16*ct + l16) * 64 + quad * 8];
            bf16x8 k1 = *(const bf16x8*)&kj[(size_t)(16*ct + l16) * 64 + 32 + quad * 8];
            f32x4 a = (f32x4)0.f;
            a = mfma16(k0, qf0, a);
            a = mfma16(k1, qf1, a);
            sacc[ct] = a;
        }
        // V^T fragments (issued early; latency hidden under softmax)
        bf16x8 vf[4][2];
        #pragma unroll
        for (int ct = 0; ct < 4; ct++) {
            vf[ct][0] = *(const bf16x8*)&vsrc[(size_t)(16*ct + l16) * 4096 + jr * 64 + quad * 8];
            vf[ct][1] = *(const bf16x8*)&vsrc[(size_t)(16*ct + l16) * 4096 + jr * 64 + 32 + quad * 8];
        }
        // softmax numerator, l-accumulate, packed P^T write
        float rh2 = LOG2E * __bfloat162float(sRH[w * 68 + jr]);
        #pragma unroll
        for (int ct = 0; ct < 4; ct++) {
            float p0 = __builtin_amdgcn_exp2f(fmaf(sacc[ct][0], SC2, rh2 + rwreg[ct][0]));
            float p1 = __builtin_amdgcn_exp2f(fmaf(sacc[ct][1], SC2, rh2 + rwreg[ct][1]));
            float p2 = __builtin_amdgcn_exp2f(fmaf(sacc[ct][2], SC2, rh2 + rwreg[ct][2]));
            float p3 = __builtin_amdgcn_exp2f(fmaf(sacc[ct][3], SC2, rh2 + rwreg[ct][3]));
            ls[ct] += (p0 + p1) + (p2 + p3);
            union { uint2 u; __hip_bfloat16 h4[4]; } pu;
            pu.h4[0]=f2bf(p0); pu.h4[1]=f2bf(p1); pu.h4[2]=f2bf(p2); pu.h4[3]=f2bf(p3);
            *(uint2*)&myPT[l16 * 72 + 16 * ct + 4 * quad] = pu.u;
        }
        // O^T += V^T . P   (B = P frags from wave-private LDS; DS in-order per wave)
        bf16x8 pf0 = *(const bf16x8*)&myPT[l16 * 72 + quad * 8];
        bf16x8 pf1 = *(const bf16x8*)&myPT[l16 * 72 + 32 + quad * 8];
        #pragma unroll
        for (int ct = 0; ct < 4; ct++) {
            oacc[ct] = mfma16(vf[ct][0], pf0, oacc[ct]);
            oacc[ct] = mfma16(vf[ct][1], pf1, oacc[ct]);
        }
    }

    float lsum = (ls[0] + ls[1]) + (ls[2] + ls[3]);
    lsum += __shfl_xor(lsum, 16, 64);
    lsum += __shfl_xor(lsum, 32, 64);

    __syncthreads();   // all sPT reads done before combine region reuse
    if (half == 1) {
        #pragma unroll
        for (int ct = 0; ct < 4; ct++)
            #pragma unroll
            for (int r = 0; r < 4; r++)
                sOx[(16*ct + 4*quad + r) * 65 + w] = oacc[ct][r];
        if (lane < 16) slx[w] = lsum;
    }
    __syncthreads();
    if (half == 0) {
        const int b = bh >> 2, head = bh & 3;
        float linv = 1.f / (lsum + slx[w]);
        float* obase = out + ((size_t)(b * 256 + head * 64)) * 4096 + h * 64;
        #pragma unroll
        for (int ct = 0; ct < 4; ct++) {
            #pragma unroll
            for (int r = 0; r < 4; r++) {
                int dv = 16 * ct + 4 * quad + r;
                obase[(size_t)dv * 4096 + w] = (oacc[ct][r] + sOx[dv * 65 + w]) * linv;
            }
        }
    }
}

extern "C" void kernel_launch(void* const* d_in, const int* in_sizes, int n_in,
                              void* d_out, int out_size, void* d_ws, size_t ws_size,
                              hipStream_t stream) {
    const float* x     = (const float*)d_in[0];
    const float* qkv_w = (const float*)d_in[1];
    const float* hrel  = (const float*)d_in[2];
    const float* wrel  = (const float*)d_in[3];
    float* out = (float*)d_out;

    // ws: qb | kb | vt (each 2M elems bf16) | xT (2M) | wb (192K)  => ~16.8 MB
    __hip_bfloat16* qb = (__hip_bfloat16*)d_ws;
    __hip_bfloat16* kb = qb + (size_t)8 * 4096 * 64;
    __hip_bfloat16* vt = kb + (size_t)8 * 4096 * 64;
    __hip_bfloat16* xT = vt + (size_t)8 * 4096 * 64;
    __hip_bfloat16* wb = xT + (size_t)2 * 4096 * 256;

    prep_kernel<<<dim3(64, 5, 2), 256, 0, stream>>>(x, qkv_w, xT, wb);
    qkv_kernel<<<dim3(64, 12, 2), 256, 0, stream>>>(xT, wb, qb, kb, vt);
    attn_kernel<<<dim3(64, 8), 512, 0, stream>>>(qb, kb, vt, hrel, wrel, out);
}

// Round 8
// 168.653 us; speedup vs baseline: 1.9332x; 1.9332x over previous
//
#include <hip/hip_runtime.h>
#include <hip/hip_bf16.h>

typedef __attribute__((ext_vector_type(8))) short bf16x8;
typedef __attribute__((ext_vector_type(4))) float f32x4;

static __device__ __forceinline__ f32x4 mfma16(bf16x8 a, bf16x8 b, f32x4 c) {
    return __builtin_amdgcn_mfma_f32_16x16x32_bf16(a, b, c, 0, 0, 0);
}

#define LOG2E 1.44269504f

static __device__ __forceinline__ __hip_bfloat16 f2bf(float f) { return __float2bfloat16(f); }

// ---------------- Kernel 0: prep ----------------
// y<4: transpose x[b][c][n] f32 -> xT[b][n][c] bf16 ; y==4: wb = bf16(qkv_w)
__global__ __launch_bounds__(256, 4) void prep_kernel(
    const float* __restrict__ x, const float* __restrict__ qkv_w,
    __hip_bfloat16* __restrict__ xT, __hip_bfloat16* __restrict__ wb)
{
    const int tid = threadIdx.x;
    if (blockIdx.y == 4) {
        int idx = (blockIdx.z * 64 + blockIdx.x) * 256 + tid;
        if (idx < 24576) {
            const float* s = qkv_w + (size_t)idx * 8;
            float4 f0 = *(const float4*)s, f1 = *(const float4*)(s + 4);
            union { bf16x8 v; __hip_bfloat16 h[8]; } u;
            u.h[0]=f2bf(f0.x); u.h[1]=f2bf(f0.y); u.h[2]=f2bf(f0.z); u.h[3]=f2bf(f0.w);
            u.h[4]=f2bf(f1.x); u.h[5]=f2bf(f1.y); u.h[6]=f2bf(f1.z); u.h[7]=f2bf(f1.w);
            *(bf16x8*)(wb + (size_t)idx * 8) = u.v;
        }
        return;
    }
    alignas(16) __shared__ __hip_bfloat16 sT[64 * 72];
    const int n0 = blockIdx.x * 64, c0 = blockIdx.y * 64, b = blockIdx.z;
    {
        int cc = tid >> 2, nq = (tid & 3) * 16;
        const float* src = x + ((size_t)b * 256 + c0 + cc) * 4096 + n0 + nq;
        #pragma unroll
        for (int i = 0; i < 4; i++) {
            float4 f = *(const float4*)(src + i * 4);
            sT[(nq + 4*i + 0) * 72 + cc] = f2bf(f.x);
            sT[(nq + 4*i + 1) * 72 + cc] = f2bf(f.y);
            sT[(nq + 4*i + 2) * 72 + cc] = f2bf(f.z);
            sT[(nq + 4*i + 3) * 72 + cc] = f2bf(f.w);
        }
    }
    __syncthreads();
    {
        int nl = tid >> 2, ch = (tid & 3) * 16;
        bf16x8 v0 = *(const bf16x8*)&sT[nl * 72 + ch];
        bf16x8 v1 = *(const bf16x8*)&sT[nl * 72 + ch + 8];
        __hip_bfloat16* dst = xT + ((size_t)b * 4096 + n0 + nl) * 256 + c0 + ch;
        *(bf16x8*)dst = v0;
        *(bf16x8*)(dst + 8) = v1;
    }
}

// ---------------- Kernel 1: QKV projection ----------------
// Stages the 64x256 x^T slab in LDS; w read direct from global (L2-hot, shared by
// 128 blocks per obq). Epilogue transposes through LDS (stride 68 -> 16B-aligned
// float4 reads) so all global stores are b128.
__global__ __launch_bounds__(256, 4) void qkv_kernel(
    const __hip_bfloat16* __restrict__ xT, const __hip_bfloat16* __restrict__ wb,
    __hip_bfloat16* __restrict__ qb, __hip_bfloat16* __restrict__ kb,
    __hip_bfloat16* __restrict__ vt)
{
    alignas(16) __shared__ unsigned char sRaw[64 * 264 * 2];  // 33792 B
    __hip_bfloat16* sX = (__hip_bfloat16*)sRaw;               // 64x264 bf16
    float* sEp = (float*)sRaw;                                // 64x68 f32 = 17408 B (reuses sX)

    const int nb = blockIdx.x * 64, obq = blockIdx.y, b = blockIdx.z;
    const int tid = threadIdx.x, lane = tid & 63, g = tid >> 6;
    const int quad = lane >> 4, l16 = lane & 15;
    const bool isV = (obq >= 8);

    {   // stage x slab: each thread covers 64 elems = 8 x bf16x8 (stride == vec width!)
        const int r = tid >> 2, c0 = (tid & 3) * 64;
        const __hip_bfloat16* xsrc = xT + ((size_t)b * 4096 + nb + r) * 256 + c0;
        #pragma unroll
        for (int i = 0; i < 8; i++)
            *(bf16x8*)&sX[r * 264 + c0 + 8 * i] = *(const bf16x8*)&xsrc[8 * i];
    }
    __syncthreads();

    const __hip_bfloat16* wB = wb + (size_t)obq * 64 * 256;

    f32x4 acc[4];
    #pragma unroll
    for (int i = 0; i < 4; i++) acc[i] = (f32x4)0.f;

    if (!isV) {   // A = x^T rows (n), B = w rows (d)
        const __hip_bfloat16* aRow = &sX[(size_t)(16 * g + l16) * 264];
        #pragma unroll
        for (int c = 0; c < 256; c += 32) {
            bf16x8 af = *(const bf16x8*)&aRow[c + quad * 8];
            #pragma unroll
            for (int ct = 0; ct < 4; ct++) {
                bf16x8 bf_ = *(const bf16x8*)&wB[(size_t)(16 * ct + l16) * 256 + c + quad * 8];
                acc[ct] = mfma16(af, bf_, acc[ct]);
            }
        }
    } else {      // A = w rows (d), B = x^T rows (n)
        const __hip_bfloat16* aRow = &wB[(size_t)(16 * g + l16) * 256];
        #pragma unroll
        for (int c = 0; c < 256; c += 32) {
            bf16x8 af = *(const bf16x8*)&aRow[c + quad * 8];
            #pragma unroll
            for (int ct = 0; ct < 4; ct++) {
                bf16x8 bf_ = *(const bf16x8*)&sX[(size_t)(16 * ct + l16) * 264 + c + quad * 8];
                acc[ct] = mfma16(af, bf_, acc[ct]);
            }
        }
    }

    __syncthreads();   // all sX reads done before sEp overwrite
    #pragma unroll
    for (int ct = 0; ct < 4; ct++)
        #pragma unroll
        for (int r = 0; r < 4; r++)
            sEp[(16 * g + 4 * quad + r) * 68 + 16 * ct + l16] = acc[ct][r];
    __syncthreads();

    {   // readback rows, pack bf16, b128 stores (row stride 272 B = 17*16: aligned)
        const int row = tid >> 2, c0e = (tid & 3) * 16;
        union { bf16x8 v[2]; __hip_bfloat16 h[16]; } u;
        #pragma unroll
        for (int i = 0; i < 4; i++) {
            float4 f = *(const float4*)&sEp[row * 68 + c0e + 4 * i];
            u.h[4*i+0]=f2bf(f.x); u.h[4*i+1]=f2bf(f.y); u.h[4*i+2]=f2bf(f.z); u.h[4*i+3]=f2bf(f.w);
        }
        if (!isV) {
            int proj = obq >> 2;
            int bh = b * 4 + (obq & 3);
            __hip_bfloat16* dst = (proj ? kb : qb) + (size_t)bh * 4096 * 64
                                  + (size_t)(nb + row) * 64 + c0e;
            *(bf16x8*)dst = u.v[0];
            *(bf16x8*)(dst + 8) = u.v[1];
        } else {
            int bh = b * 4 + (obq - 8);
            __hip_bfloat16* dst = vt + ((size_t)(bh * 64 + row)) * 4096 + nb + c0e;
            *(bf16x8*)dst = u.v[0];
            *(bf16x8*)(dst + 8) = u.v[1];
        }
    }
}

// ---------------- Kernel 2: fused flash attention (R3 verbatim - passed @88us) ----------------
__global__ __launch_bounds__(512, 4) void attn_kernel(
    const __hip_bfloat16* __restrict__ qb, const __hip_bfloat16* __restrict__ kb,
    const __hip_bfloat16* __restrict__ vt, const float* __restrict__ hrel,
    const float* __restrict__ wrel, float* __restrict__ out)
{
    alignas(16) __shared__ __hip_bfloat16 sU[384 * 72];   // 55296 B union
    alignas(16) __shared__ __hip_bfloat16 sRH[64 * 66];   // 8448 B persistent rh bias

    const int h    = blockIdx.x;
    const int bh   = blockIdx.y;
    const int tid  = threadIdx.x;
    const int lane = tid & 63;
    const int wv   = tid >> 6;      // 0..7
    const int half = wv >> 2;       // key half
    const int g    = wv & 3;        // query row group (rows 16g..16g+15)
    const int quad = lane >> 4;
    const int l16  = lane & 15;

    // prologue layout
    __hip_bfloat16* sQ   = sU;              // 64x72
    __hip_bfloat16* sW   = sU + 64 * 72;    // 128x72 (wrel, row 127 zeroed)
    __hip_bfloat16* sHRs = sU + 192 * 72;   // 64x72 (shifted hrel)
    __hip_bfloat16* sRWt = sU;              // 64x66 gather scratch (reuses sQ)

    // main-loop layout (per half)
    __hip_bfloat16* sKb = sU + (half ? 192 : 0) * 72;
    __hip_bfloat16* sVb = sKb + 64 * 72;
    __hip_bfloat16* sPb = sKb + 128 * 72;

    // ---- prologue staging ----
    {   // Q: 64x64 bf16 contiguous
        int r = tid >> 3, d8 = (tid & 7) * 8;
        *(bf16x8*)&sQ[r * 72 + d8] =
            *(const bf16x8*)&qb[(((size_t)bh * 4096 + h * 64 + r)) * 64 + d8];
    }
    {   // wrel: 127x64 f32 -> bf16 (row 127 zero)
        int r = tid >> 2, c0 = (tid & 3) << 4;
        union { bf16x8 v; __hip_bfloat16 h8[8]; } u0, u1;
        #pragma unroll
        for (int i = 0; i < 2; i++) {
            float4 f = (r < 127) ? *(const float4*)&wrel[r * 64 + c0 + 4*i] : float4{0,0,0,0};
            u0.h8[4*i+0]=f2bf(f.x); u0.h8[4*i+1]=f2bf(f.y); u0.h8[4*i+2]=f2bf(f.z); u0.h8[4*i+3]=f2bf(f.w);
        }
        #pragma unroll
        for (int i = 0; i < 2; i++) {
            float4 f = (r < 127) ? *(const float4*)&wrel[r * 64 + c0 + 8 + 4*i] : float4{0,0,0,0};
            u1.h8[4*i+0]=f2bf(f.x); u1.h8[4*i+1]=f2bf(f.y); u1.h8[4*i+2]=f2bf(f.z); u1.h8[4*i+3]=f2bf(f.w);
        }
        *(bf16x8*)&sW[r * 72 + c0]     = u0.v;
        *(bf16x8*)&sW[r * 72 + c0 + 8] = u1.v;
    }
    {   // hrel rows [63-h, 127-h) -> sHRs[hp][d]
        int r = tid >> 3, c0 = (tid & 7) << 3;
        union { bf16x8 v; __hip_bfloat16 h8[8]; } u0;
        #pragma unroll
        for (int i = 0; i < 2; i++) {
            float4 f = *(const float4*)&hrel[(63 - h + r) * 64 + c0 + 4*i];
            u0.h8[4*i+0]=f2bf(f.x); u0.h8[4*i+1]=f2bf(f.y); u0.h8[4*i+2]=f2bf(f.z); u0.h8[4*i+3]=f2bf(f.w);
        }
        *(bf16x8*)&sHRs[r * 72 + c0] = u0.v;
    }
    __syncthreads();

    // Q fragments (rows 16g..16g+15; same for both halves)
    const __hip_bfloat16* aRow = &sQ[(16 * g + l16) * 72];
    bf16x8 qf0 = *(const bf16x8*)&aRow[quad * 8];
    bf16x8 qf1 = *(const bf16x8*)&aRow[32 + quad * 8];
    __syncthreads();   // all frags read before sRWt overwrites sQ

    // rw gather: X[w][rr] = Q . wrel[rr]; scatter wp = rr + w - 63.
    {
        const int rbase = half * 64;
        #pragma unroll
        for (int ct = 0; ct < 4; ct++) {
            int rr = rbase + 16 * ct + l16;
            f32x4 a = (f32x4)0.f;
            a = mfma16(qf0, *(const bf16x8*)&sW[rr * 72 + quad * 8], a);
            a = mfma16(qf1, *(const bf16x8*)&sW[rr * 72 + 32 + quad * 8], a);
            #pragma unroll
            for (int r = 0; r < 4; r++) {
                int ww = 16 * g + quad * 4 + r;
                int wp = rr + ww - 63;
                if (wp >= 0 && wp < 64) sRWt[ww * 66 + wp] = f2bf(a[r]);
            }
        }
    }
    // rh bias (waves 0-3 only): sRH[w][h'] = Q . sHRs[h']
    if (half == 0) {
        #pragma unroll
        for (int ct = 0; ct < 4; ct++) {
            f32x4 a = (f32x4)0.f;
            a = mfma16(qf0, *(const bf16x8*)&sHRs[(16 * ct + l16) * 72 + quad * 8], a);
            a = mfma16(qf1, *(const bf16x8*)&sHRs[(16 * ct + l16) * 72 + 32 + quad * 8], a);
            #pragma unroll
            for (int r = 0; r < 4; r++)
                sRH[(16 * g + quad * 4 + r) * 66 + 16 * ct + l16] = f2bf(a[r]);
        }
    }
    __syncthreads();

    // hoist rw to registers, pre-scaled by log2(e)
    float rwreg[4][4];
    #pragma unroll
    for (int ct = 0; ct < 4; ct++)
        #pragma unroll
        for (int r = 0; r < 4; r++)
            rwreg[ct][r] = LOG2E * __bfloat162float(
                sRWt[(16 * g + quad * 4 + r) * 66 + 16 * ct + l16]);
    __syncthreads();   // sRWt/sW/sHRs now dead; main loop owns sU

    f32x4 oacc[4];
    for (int ct = 0; ct < 4; ct++) oacc[ct] = (f32x4)0.f;
    float lsum[4] = {0.f, 0.f, 0.f, 0.f};

    const __hip_bfloat16* ksrc = kb + (size_t)bh * 4096 * 64;
    const __hip_bfloat16* vsrc = vt + (size_t)bh * 64 * 4096;

    // staging: 256 threads per half stage that half's K/V (2x b128 each)
    const int tloc = tid & 255;
    const int sr0 = tloc >> 3, sd0 = (tloc & 7) * 8;          // rows 0..31
    const int sr1 = 32 + sr0;                                  // rows 32..63

    bf16x8 pk0, pk1, pv0, pv1;
    {
        int jr = half * 32;
        pk0 = *(const bf16x8*)&ksrc[(size_t)(jr * 64 + sr0) * 64 + sd0];
        pk1 = *(const bf16x8*)&ksrc[(size_t)(jr * 64 + sr1) * 64 + sd0];
        pv0 = *(const bf16x8*)&vsrc[(size_t)sr0 * 4096 + jr * 64 + sd0];
        pv1 = *(const bf16x8*)&vsrc[(size_t)sr1 * 4096 + jr * 64 + sd0];
    }

    for (int j = 0; j < 32; j++) {
        const int jr = half * 32 + j;
        *(bf16x8*)&sKb[sr0 * 72 + sd0] = pk0;
        *(bf16x8*)&sKb[sr1 * 72 + sd0] = pk1;
        *(bf16x8*)&sVb[sr0 * 72 + sd0] = pv0;
        *(bf16x8*)&sVb[sr1 * 72 + sd0] = pv1;
        __syncthreads();
        if (j < 31) {   // prefetch next key row
            int jn = jr + 1;
            pk0 = *(const bf16x8*)&ksrc[(size_t)(jn * 64 + sr0) * 64 + sd0];
            pk1 = *(const bf16x8*)&ksrc[(size_t)(jn * 64 + sr1) * 64 + sd0];
            pv0 = *(const bf16x8*)&vsrc[(size_t)sr0 * 4096 + jn * 64 + sd0];
            pv1 = *(const bf16x8*)&vsrc[(size_t)sr1 * 4096 + jn * 64 + sd0];
        }

        // S = Q K^T
        f32x4 sacc[4];
        #pragma unroll
        for (int ct = 0; ct < 4; ct++) {
            f32x4 a = (f32x4)0.f;
            a = mfma16(qf0, *(const bf16x8*)&sKb[(16 * ct + l16) * 72 + quad * 8], a);
            a = mfma16(qf1, *(const bf16x8*)&sKb[(16 * ct + l16) * 72 + 32 + quad * 8], a);
            sacc[ct] = a;
        }
        // p = exp2(s*scale*log2e + (rh+rw)*log2e); accumulate l per-lane
        float rh2[4];
        #pragma unroll
        for (int r = 0; r < 4; r++)
            rh2[r] = LOG2E * __bfloat162float(sRH[(16 * g + quad * 4 + r) * 66 + jr]);
        #pragma unroll
        for (int ct = 0; ct < 4; ct++) {
            int col = 16 * ct + l16;
            #pragma unroll
            for (int r = 0; r < 4; r++) {
                int ww = 16 * g + quad * 4 + r;
                float p = __builtin_amdgcn_exp2f(
                    fmaf(sacc[ct][r], 0.125f * LOG2E, rh2[r] + rwreg[ct][r]));
                lsum[r] += p;
                sPb[ww * 72 + col] = f2bf(p);
            }
        }
        // O += P V   (P rows are wave-private: no barrier needed, lgkmcnt suffices)
        const __hip_bfloat16* pRow = &sPb[(16 * g + l16) * 72];
        #pragma unroll
        for (int ks = 0; ks < 2; ks++) {
            bf16x8 pf = *(const bf16x8*)&pRow[ks * 32 + quad * 8];
            #pragma unroll
            for (int ct = 0; ct < 4; ct++) {
                bf16x8 vf = *(const bf16x8*)&sVb[(16 * ct + l16) * 72 + ks * 32 + quad * 8];
                oacc[ct] = mfma16(pf, vf, oacc[ct]);
            }
        }
        __syncthreads();
    }

    // reduce l across the 16 column-lanes (full row-sum within this half)
    #pragma unroll
    for (int off = 1; off < 16; off <<= 1)
        #pragma unroll
        for (int r = 0; r < 4; r++)
            lsum[r] += __shfl_xor(lsum[r], off, 64);

    // combine halves through LDS
    __syncthreads();
    float* sOx = (float*)sU;            // 64x65 f32
    float* slx = sOx + 64 * 65;         // 64 f32
    if (half == 1) {
        #pragma unroll
        for (int ct = 0; ct < 4; ct++)
            #pragma unroll
            for (int r = 0; r < 4; r++)
                sOx[(16 * g + quad * 4 + r) * 65 + 16 * ct + l16] = oacc[ct][r];
        if (l16 == 0)
            #pragma unroll
            for (int r = 0; r < 4; r++) slx[16 * g + quad * 4 + r] = lsum[r];
    }
    __syncthreads();
    if (half == 0) {
        const int b = bh >> 2, head = bh & 3;
        float linv[4];
        #pragma unroll
        for (int r = 0; r < 4; r++)
            linv[r] = 1.f / (lsum[r] + slx[16 * g + quad * 4 + r]);
        #pragma unroll
        for (int ct = 0; ct < 4; ct++) {
            int dv = 16 * ct + l16;
            #pragma unroll
            for (int r = 0; r < 4; r++) {
                int ww = 16 * g + quad * 4 + r;
                float o = oacc[ct][r] + sOx[ww * 65 + dv];
                out[((size_t)(b * 256 + head * 64 + dv)) * 4096 + h * 64 + ww] = o * linv[r];
            }
        }
    }
}

extern "C" void kernel_launch(void* const* d_in, const int* in_sizes, int n_in,
                              void* d_out, int out_size, void* d_ws, size_t ws_size,
                              hipStream_t stream) {
    const float* x     = (const float*)d_in[0];
    const float* qkv_w = (const float*)d_in[1];
    const float* hrel  = (const float*)d_in[2];
    const float* wrel  = (const float*)d_in[3];
    float* out = (float*)d_out;

    __hip_bfloat16* qb = (__hip_bfloat16*)d_ws;
    __hip_bfloat16* kb = qb + (size_t)8 * 4096 * 64;
    __hip_bfloat16* vt = kb + (size_t)8 * 4096 * 64;
    __hip_bfloat16* xT = vt + (size_t)8 * 4096 * 64;
    __hip_bfloat16* wb = xT + (size_t)2 * 4096 * 256;

    prep_kernel<<<dim3(64, 5, 2), 256, 0, stream>>>(x, qkv_w, xT, wb);
    qkv_kernel<<<dim3(64, 12, 2), 256, 0, stream>>>(xT, wb, qb, kb, vt);
    attn_kernel<<<dim3(64, 8), 512, 0, stream>>>(qb, kb, vt, hrel, wrel, out);
}